// Round 8
// baseline (534.435 us; speedup 1.0000x reference)
//
#include <hip/hip_runtime.h>

#define NN 50000
#define NE 800000
#define NT 12500     // 64-edge tiles
#define E1B 1788     // E1 blocks
#define E1T 7        // tiles per E1 block (1788*7 >= 12500)

typedef _Float16 half8 __attribute__((ext_vector_type(8)));
typedef _Float16 half2v __attribute__((ext_vector_type(2)));
typedef float f32x4 __attribute__((ext_vector_type(4)));

__device__ __forceinline__ float sigm(float x) { return 1.0f / (1.0f + __expf(-x)); }

// ---------- zero cnt (replaces hipMemsetAsync) ----------
__global__ void zeroc_kernel(unsigned* __restrict__ cnt) {
  int i = blockIdx.x * 256 + threadIdx.x;
  if (i < NN) cnt[i] = 0u;
}

// ---------- prep: W (f32 [k][n] 128x128) -> W^T (f16 [n][k]) in ws ----------
__global__ void prepw_kernel(const float* __restrict__ w0, const float* __restrict__ w1,
                             const float* __restrict__ w2, _Float16* __restrict__ wt) {
  const float* w = blockIdx.x == 0 ? w0 : (blockIdx.x == 1 ? w1 : w2);
  _Float16* o = wt + blockIdx.x * 16384;
  int t = threadIdx.x;
  for (int it = 0; it < 64; ++it) {
    int flat = it * 256 + t;
    int k = flat >> 7, n = flat & 127;
    o[n * 128 + k] = (_Float16)w[flat];
  }
}

// ---------- degree histogram ----------
__global__ void hist_kernel(const int* __restrict__ eidx, unsigned* __restrict__ cnt) {
  int e = blockIdx.x * 256 + threadIdx.x;
  if (e < NE) atomicAdd(&cnt[eidx[2 * e]], 1u);
}

// ---------- exclusive prefix scan: cnt -> cursor & cstart ----------
__global__ __launch_bounds__(1024) void scan_kernel(const unsigned* __restrict__ cnt,
                                                    unsigned* __restrict__ cursor,
                                                    unsigned* __restrict__ cstart) {
  __shared__ unsigned part[1024];
  const int t = threadIdx.x;
  const int CH = 49;                  // 1024*49 = 50176 >= NN
  int base = t * CH;
  unsigned s = 0;
  for (int i = 0; i < CH; ++i) { int j = base + i; if (j < NN) s += cnt[j]; }
  part[t] = s;
  __syncthreads();
  for (int off = 1; off < 1024; off <<= 1) {
    unsigned v = (t >= off) ? part[t - off] : 0u;
    __syncthreads();
    part[t] += v;
    __syncthreads();
  }
  unsigned run = (t > 0) ? part[t - 1] : 0u;
  for (int i = 0; i < CH; ++i) {
    int j = base + i;
    if (j < NN) { cursor[j] = run; cstart[j] = run; run += cnt[j]; }
  }
}

// ---------- counting-sort scatter: sdst[pos]=dst, rank[e]=pos ----------
__global__ void scatter_kernel(const int* __restrict__ eidx, unsigned* __restrict__ cursor,
                               int* __restrict__ sdst, int* __restrict__ rank) {
  int e = blockIdx.x * 256 + threadIdx.x;
  if (e >= NE) return;
  int s = eidx[2 * e], d = eidx[2 * e + 1];
  unsigned pos = atomicAdd(&cursor[s], 1u);
  sdst[pos] = d;
  rank[e] = (int)pos;
}

// ---------- node GEMM: nh16 = f16(nf @ Wn + bn) ----------
__global__ __launch_bounds__(512, 2) void node_kernel(
    const float* __restrict__ nf, const _Float16* __restrict__ wnT,
    const float* __restrict__ bnp, _Float16* __restrict__ nh16) {
  __shared__ __align__(16) char wl[32768];
  __shared__ __align__(16) char tl[65536];

  const int t = threadIdx.x;
  const int lane = t & 63;
  const int wave = t >> 6;
  const int wm = wave >> 2;
  const int wn = wave & 3;

  for (int it = 0; it < 4; ++it) {
    int h8 = it * 512 + t;
    int n = h8 >> 4, k8 = h8 & 15;
    half8 v = *(const half8*)(wnT + n * 128 + k8 * 8);
    *(half8*)(wl + ((n * 256 + k8 * 16) ^ ((n & 7) << 4))) = v;
  }

  const int row0 = blockIdx.x * 256;
  for (int it = 0; it < 8; ++it) {
    int idx8 = it * 512 + t;
    int row = idx8 >> 4, col8 = idx8 & 15;
    int grow = row0 + row;
    half8 h;
    if (grow < NN) {
      const float4* s = (const float4*)(nf + (size_t)grow * 128 + col8 * 8);
      float4 a = s[0], b = s[1];
      h[0] = (_Float16)a.x; h[1] = (_Float16)a.y; h[2] = (_Float16)a.z; h[3] = (_Float16)a.w;
      h[4] = (_Float16)b.x; h[5] = (_Float16)b.y; h[6] = (_Float16)b.z; h[7] = (_Float16)b.w;
    } else {
#pragma unroll
      for (int j = 0; j < 8; ++j) h[j] = (_Float16)0.0f;
    }
    *(half8*)(tl + ((row * 256 + col8 * 16) ^ ((row & 7) << 4))) = h;
  }
  __syncthreads();

  const int c0 = wn * 32 + (lane & 15);
  const int arow = wm * 128 + (lane & 15);
  const int akb = (lane >> 4) * 16;

  f32x4 acc[8][2] = {};
#pragma unroll
  for (int ks = 0; ks < 4; ++ks) {
    int kb = ks * 64 + akb;
    half8 B0 = *(half8*)(wl + c0 * 256 + (kb ^ ((c0 & 7) << 4)));
    half8 B1 = *(half8*)(wl + (c0 + 16) * 256 + (kb ^ ((c0 & 7) << 4)));
#pragma unroll
    for (int mi = 0; mi < 8; ++mi) {
      int r = arow + mi * 16;
      half8 A = *(half8*)(tl + r * 256 + (kb ^ ((r & 7) << 4)));
      acc[mi][0] = __builtin_amdgcn_mfma_f32_16x16x32_f16(A, B0, acc[mi][0], 0, 0, 0);
      acc[mi][1] = __builtin_amdgcn_mfma_f32_16x16x32_f16(A, B1, acc[mi][1], 0, 0, 0);
    }
  }

  const float b0 = bnp[c0], b1 = bnp[c0 + 16];
#pragma unroll
  for (int mi = 0; mi < 8; ++mi) {
#pragma unroll
    for (int r = 0; r < 4; ++r) {
      int grow = row0 + wm * 128 + mi * 16 + (lane >> 4) * 4 + r;
      if (grow < NN) {
        nh16[(size_t)grow * 128 + c0] = (_Float16)(acc[mi][0][r] + b0);
        nh16[(size_t)grow * 128 + c0 + 16] = (_Float16)(acc[mi][1][r] + b1);
      }
    }
  }
}

// ---------- E1: streaming dual GEMM, B in regs; P rows repacked in LDS and
// stored as coalesced 256-B rows directly into src-sorted slots (rank) ----------
__global__ __launch_bounds__(512, 4) void e1_kernel(
    const float* __restrict__ ef, const int* __restrict__ rank,
    const _Float16* __restrict__ wgT, const _Float16* __restrict__ wfT,
    const float* __restrict__ bgp, const float* __restrict__ bfp,
    _Float16* __restrict__ P) {
  __shared__ __align__(16) char tl[2][16384];   // A-tiles, dbuf
  __shared__ __align__(16) char tp[16384];      // P repack tile
  __shared__ int rk[64];

  const int t = threadIdx.x;
  const int lane = t & 63;
  const int w = t >> 6;        // wave 0..7 -> 16-col slice
  const int lc = lane & 15;
  const int q = lane >> 4;     // 0..3

  // B fragments in registers, loaded ONCE per block
  const int col = w * 16 + lc;
  half8 Bg[4], Bf[4];
#pragma unroll
  for (int ks = 0; ks < 4; ++ks) {
    Bg[ks] = *(const half8*)(wgT + (size_t)col * 128 + ks * 32 + q * 8);
    Bf[ks] = *(const half8*)(wfT + (size_t)col * 128 + ks * 32 + q * 8);
  }
  const float bgv = bgp[col], bfv = bfp[col];

  int first = blockIdx.x * E1T;
  int last = first + E1T; if (last > NT) last = NT;
  if (first >= NT) return;

  float4 r0a, r0b, r1a, r1b;   // staging registers

#define LOADR(tile)                                                              \
  {                                                                              \
    const float* b0_ = ef + (size_t)((tile) * 64 + (t >> 4)) * 128 + (t & 15) * 8; \
    r0a = *(const float4*)b0_; r0b = *(const float4*)(b0_ + 4);                  \
    const float* b1_ = b0_ + (size_t)32 * 128;                                   \
    r1a = *(const float4*)b1_; r1b = *(const float4*)(b1_ + 4);                  \
  }

#define WRITEB(bf_)                                                              \
  {                                                                              \
    int row_ = t >> 4, c16_ = (t & 15) * 16;                                     \
    half8 h_;                                                                    \
    h_[0]=(_Float16)r0a.x; h_[1]=(_Float16)r0a.y; h_[2]=(_Float16)r0a.z; h_[3]=(_Float16)r0a.w; \
    h_[4]=(_Float16)r0b.x; h_[5]=(_Float16)r0b.y; h_[6]=(_Float16)r0b.z; h_[7]=(_Float16)r0b.w; \
    *(half8*)(tl[bf_] + ((row_ * 256 + c16_) ^ ((row_ & 7) << 4))) = h_;         \
    row_ += 32;                                                                  \
    h_[0]=(_Float16)r1a.x; h_[1]=(_Float16)r1a.y; h_[2]=(_Float16)r1a.z; h_[3]=(_Float16)r1a.w; \
    h_[4]=(_Float16)r1b.x; h_[5]=(_Float16)r1b.y; h_[6]=(_Float16)r1b.z; h_[7]=(_Float16)r1b.w; \
    *(half8*)(tl[bf_] + ((row_ * 256 + c16_) ^ ((row_ & 7) << 4))) = h_;         \
  }

  LOADR(first);
  WRITEB(0);
  __syncthreads();
  int buf = 0;

  for (int i = first; i < last; ++i) {
    const bool more = (i + 1 < last);
    if (more) LOADR(i + 1);        // issue next-tile loads early (T14)

    // MFMA tile i from tl[buf]
    f32x4 ag[4] = {}, af[4] = {};
#pragma unroll
    for (int ks = 0; ks < 4; ++ks) {
#pragma unroll
      for (int mi = 0; mi < 4; ++mi) {
        int r = mi * 16 + lc;
        half8 A = *(half8*)(tl[buf] + ((r * 256 + ks * 64 + q * 16) ^ ((r & 7) << 4)));
        ag[mi] = __builtin_amdgcn_mfma_f32_16x16x32_f16(A, Bg[ks], ag[mi], 0, 0, 0);
        af[mi] = __builtin_amdgcn_mfma_f32_16x16x32_f16(A, Bf[ks], af[mi], 0, 0, 0);
      }
    }

    // epilogue: P = sigm(gate)*filt -> f16 into repack tile (swizzled by row)
#pragma unroll
    for (int mi = 0; mi < 4; ++mi) {
#pragma unroll
      for (int rr = 0; rr < 4; ++rr) {
        int el = mi * 16 + q * 4 + rr;
        float pv = sigm(ag[mi][rr] + bgv) * (af[mi][rr] + bfv);
        *(_Float16*)(tp + el * 256 + ((col * 2) ^ ((el & 7) << 4))) = (_Float16)pv;
      }
    }
    if (t < 64) rk[t] = rank[i * 64 + t];
    __syncthreads();   // tp complete, rk visible, all done reading tl[buf]

    // store repacked rows coalesced: 8 threads x 32B per row -> rank slot
    {
      int el = t >> 3;
      int cb = (t & 7) * 32;
      int sw = (el & 7) << 4;
      const char* base = tp + el * 256;
      float4 v0 = *(const float4*)(base + ((cb + 0) ^ sw));
      float4 v1 = *(const float4*)(base + ((cb + 16) ^ sw));
      char* dst = (char*)(P + (size_t)rk[el] * 128) + cb;
      *(float4*)(dst + 0) = v0;
      *(float4*)(dst + 16) = v1;
    }

    if (more) WRITEB(buf ^ 1);     // vmcnt wait folds here via data dep
    __syncthreads();               // tl[buf^1] ready; tp drained for next iter
    buf ^= 1;
  }
#undef LOADR
#undef WRITEB
}

// ---------- E2: CSR per-src wave; STREAM sorted P run, gather nh16[dst]; BN+ReLU ----------
__global__ __launch_bounds__(256) void e2_kernel(
    const _Float16* __restrict__ P, const int* __restrict__ sdst,
    const unsigned* __restrict__ cstart, const unsigned* __restrict__ cnt,
    const _Float16* __restrict__ nh16,
    const float* __restrict__ gamma, const float* __restrict__ beta,
    const float* __restrict__ mean, const float* __restrict__ var,
    float* __restrict__ out) {
  int s = blockIdx.x * 4 + (threadIdx.x >> 6);
  if (s >= NN) return;
  const int lane = threadIdx.x & 63;
  const int c = lane * 2;

  const unsigned start = cstart[s];
  const int deg = (int)cnt[s];
  const unsigned end = start + (unsigned)deg;

  const _Float16* __restrict__ Pc = P + c;
  const _Float16* __restrict__ Nc = nh16 + c;

  float a0 = 0.0f, a1 = 0.0f;
  unsigned p = start;
  for (; p + 4 <= end; p += 4) {
    int d0 = sdst[p], d1 = sdst[p + 1], d2 = sdst[p + 2], d3 = sdst[p + 3];
    half2v P0 = *(const half2v*)(Pc + (size_t)p * 128);
    half2v P1 = *(const half2v*)(Pc + (size_t)(p + 1) * 128);
    half2v P2 = *(const half2v*)(Pc + (size_t)(p + 2) * 128);
    half2v P3 = *(const half2v*)(Pc + (size_t)(p + 3) * 128);
    half2v N0 = *(const half2v*)(Nc + (size_t)d0 * 128);
    half2v N1 = *(const half2v*)(Nc + (size_t)d1 * 128);
    half2v N2 = *(const half2v*)(Nc + (size_t)d2 * 128);
    half2v N3 = *(const half2v*)(Nc + (size_t)d3 * 128);
    a0 += (float)P0[0] * (float)N0[0]; a1 += (float)P0[1] * (float)N0[1];
    a0 += (float)P1[0] * (float)N1[0]; a1 += (float)P1[1] * (float)N1[1];
    a0 += (float)P2[0] * (float)N2[0]; a1 += (float)P2[1] * (float)N2[1];
    a0 += (float)P3[0] * (float)N3[0]; a1 += (float)P3[1] * (float)N3[1];
  }
  for (; p < end; ++p) {
    int d = sdst[p];
    half2v Pp = *(const half2v*)(Pc + (size_t)p * 128);
    half2v Np = *(const half2v*)(Nc + (size_t)d * 128);
    a0 += (float)Pp[0] * (float)Np[0];
    a1 += (float)Pp[1] * (float)Np[1];
  }

  float inv = deg > 0 ? 1.0f / (float)deg : 0.0f;
  half2v H = *(const half2v*)(Nc + (size_t)s * 128);
  float x0 = (float)H[0] + a0 * inv;
  float x1 = (float)H[1] + a1 * inv;
  float sc0 = rsqrtf(var[c] + 0.001f) * gamma[c];
  float sc1 = rsqrtf(var[c + 1] + 0.001f) * gamma[c + 1];
  float v0 = (x0 - mean[c]) * sc0 + beta[c];
  float v1 = (x1 - mean[c + 1]) * sc1 + beta[c + 1];
  float2 o;
  o.x = fmaxf(v0, 0.0f);
  o.y = fmaxf(v1, 0.0f);
  *(float2*)(out + (size_t)s * 128 + c) = o;
}

extern "C" void kernel_launch(void* const* d_in, const int* in_sizes, int n_in,
                              void* d_out, int out_size, void* d_ws, size_t ws_size,
                              hipStream_t stream) {
  const float* nf    = (const float*)d_in[0];
  const float* ef    = (const float*)d_in[1];
  const float* Wn    = (const float*)d_in[2];
  const float* bn    = (const float*)d_in[3];
  const float* Wg    = (const float*)d_in[4];
  const float* bg    = (const float*)d_in[5];
  const float* Wf    = (const float*)d_in[6];
  const float* bf    = (const float*)d_in[7];
  const float* gamma = (const float*)d_in[8];
  const float* beta  = (const float*)d_in[9];
  const float* mean  = (const float*)d_in[10];
  const float* var   = (const float*)d_in[11];
  const int*   eidx  = (const int*)d_in[12];
  float* out = (float*)d_out;
  char* ws = (char*)d_ws;

  _Float16* nh16   = (_Float16*)(ws + 0);            //  12,800,000
  _Float16* P16    = (_Float16*)(ws + 12800000);     // 204,800,000
  unsigned* cnt    = (unsigned*)(ws + 217600000);    //     200,000
  unsigned* cstart = (unsigned*)(ws + 217800000);    //     200,000
  unsigned* cursor = (unsigned*)(ws + 218000000);    //     200,000
  _Float16* wt     = (_Float16*)(ws + 218200000);    //      98,304
  int*      sdst   = (int*)(ws + 218300000);         //   3,200,000
  int*      rank   = (int*)(ws + 221500000);         //   3,200,000  -> end 224,700,000

  zeroc_kernel<<<(NN + 255) / 256, 256, 0, stream>>>(cnt);
  prepw_kernel<<<3, 256, 0, stream>>>(Wn, Wg, Wf, wt);
  hist_kernel<<<NE / 256, 256, 0, stream>>>(eidx, cnt);
  scan_kernel<<<1, 1024, 0, stream>>>(cnt, cursor, cstart);
  scatter_kernel<<<NE / 256, 256, 0, stream>>>(eidx, cursor, sdst, rank);
  node_kernel<<<(NN + 255) / 256, 512, 0, stream>>>(nf, wt, bn, nh16);
  e1_kernel<<<E1B, 512, 0, stream>>>(ef, rank, wt + 16384, wt + 32768, bg, bf, P16);
  e2_kernel<<<(NN + 3) / 4, 256, 0, stream>>>(P16, sdst, cstart, cnt, nh16,
                                              gamma, beta, mean, var, out);
}